// Round 10
// baseline (159.713 us; speedup 1.0000x reference)
//
#include <hip/hip_runtime.h>
#include <math.h>

#define C_   256
#define B_   4
#define T_   4
#define AH_  32
#define AW_  32
#define VH_  56
#define VW_  56
#define AHW  (AH_*AW_)          // 1024
#define VHW  (VH_*VW_)          // 3136
#define NA_  (B_*C_*AHW)        // 1,048,576
#define NV_  (B_*T_*C_*VHW)     // 12,845,056
#define NAV_ (B_*C_*VHW)        // 3,211,264

typedef unsigned short u16;
typedef short s16x8 __attribute__((ext_vector_type(8)));
typedef unsigned short u16x8 __attribute__((ext_vector_type(8)));
typedef unsigned short u16x4 __attribute__((ext_vector_type(4)));
typedef float f32x4 __attribute__((ext_vector_type(4)));

__device__ __forceinline__ u16 f2b(float f) {            // fp32 -> bf16 RNE
  unsigned u = __float_as_uint(f);
  u += 0x7FFFu + ((u >> 16) & 1u);
  return (u16)(u >> 16);
}
__device__ __forceinline__ float b2f(u16 h) {
  return __uint_as_float((unsigned)h << 16);
}
// tanh-form GELU: x*sigma(1.5957691*x + 0.07135482*x^3); |err| vs exact ~3e-4
__device__ __forceinline__ float gelu_f(float x) {
  float x2 = x * x;
  float e = __expf(x * (-1.5957691216f - 0.0713548162f * x2));
  return x * __builtin_amdgcn_rcpf(1.f + e);
}
__device__ __forceinline__ float sigmoid_f(float x) {
  return __builtin_amdgcn_rcpf(1.f + __expf(-x));
}

// ---------------- fp32 -> bf16 convert, all 4 weight matrices --------------
__global__ __launch_bounds__(256) void cvt_bf16_4(
    const float* __restrict__ s0, const float* __restrict__ s1,
    const float* __restrict__ s2, const float* __restrict__ s3,
    u16* __restrict__ dst)
{
  int g = blockIdx.x >> 5;
  const float* src = (g == 0) ? s0 : (g == 1) ? s1 : (g == 2) ? s2 : s3;
  size_t i = ((size_t)(blockIdx.x & 31) * 256 + threadIdx.x) * 8;
  float4 v0 = *(const float4*)(src + i);
  float4 v1 = *(const float4*)(src + i + 4);
  u16x8 o = {f2b(v0.x), f2b(v0.y), f2b(v0.z), f2b(v0.w),
             f2b(v1.x), f2b(v1.y), f2b(v1.z), f2b(v1.w)};
  *(u16x8*)(dst + (size_t)g * 65536 + i) = o;
}

// ---------------- GroupNorm(1,C) stats: merged a+v, 2-stage ----------------
__global__ __launch_bounds__(256) void gn_reduce1m(
    const float* __restrict__ a, const float* __restrict__ v,
    float* __restrict__ part)
{
  int samp = blockIdx.y, chunk = blockIdx.x;
  const float* x; int per;
  if (samp < 4) { x = a + (size_t)samp * (C_ * AHW); per = (C_ * AHW / 4) / 128; }
  else          { x = v + (size_t)(samp - 4) * (C_ * VHW); per = (C_ * VHW / 4) / 128; }
  const float4* xb = (const float4*)x + (size_t)chunk * per;
  float s = 0.f, s2 = 0.f;
  for (int i = threadIdx.x; i < per; i += 256) {
    float4 q = xb[i];
    s  += q.x + q.y + q.z + q.w;
    s2 += q.x*q.x + q.y*q.y + q.z*q.z + q.w*q.w;
  }
  __shared__ float sh1[256], sh2[256];
  sh1[threadIdx.x] = s; sh2[threadIdx.x] = s2;
  __syncthreads();
  for (int st = 128; st > 0; st >>= 1) {
    if (threadIdx.x < st) {
      sh1[threadIdx.x] += sh1[threadIdx.x + st];
      sh2[threadIdx.x] += sh2[threadIdx.x + st];
    }
    __syncthreads();
  }
  if (threadIdx.x == 0) {
    part[(samp * 128 + chunk) * 2 + 0] = sh1[0];
    part[(samp * 128 + chunk) * 2 + 1] = sh2[0];
  }
}

__global__ __launch_bounds__(128) void gn_reduce2m(
    const float* __restrict__ part, float* __restrict__ stats)
{
  int samp = blockIdx.x;
  int t = threadIdx.x;
  __shared__ float sh1[128], sh2[128];
  sh1[t] = part[(samp * 128 + t) * 2 + 0];
  sh2[t] = part[(samp * 128 + t) * 2 + 1];
  __syncthreads();
  for (int st = 64; st > 0; st >>= 1) {
    if (t < st) { sh1[t] += sh1[t + st]; sh2[t] += sh2[t + st]; }
    __syncthreads();
  }
  if (t == 0) {
    float invN = (samp < 4) ? 1.f / (float)(C_ * AHW) : 1.f / (float)(C_ * VHW);
    float mu  = sh1[0] * invN;
    float var = sh2[0] * invN - mu * mu;
    stats[samp * 2 + 0] = mu;
    stats[samp * 2 + 1] = rsqrtf(var + 1e-5f);
  }
}

// ---------------- merged GN+dwconv: a-path (blocks 0..1023) + v-path -------
__global__ __launch_bounds__(256) void gn_dwconv_all(
    const float* __restrict__ xa, const float* __restrict__ xv,
    const float* __restrict__ stats,
    const float* __restrict__ a_gn_w, const float* __restrict__ a_gn_b,
    const float* __restrict__ a_dw7, const float* __restrict__ a_dw3,
    const float* __restrict__ v_gn_w, const float* __restrict__ v_gn_b,
    const float* __restrict__ v_dw7, const float* __restrict__ v_dw3,
    u16* __restrict__ outa, u16* __restrict__ outv)
{
  __shared__ float tile[62 * 64];
  __shared__ float comb[49];
  const int t = threadIdx.x;
  if (blockIdx.x < 1024) {
    // ----- a-path: H=W=32, TWP=44, RPT=2, 128 compute threads -----
    constexpr int TH = 38, TW = 38, TWP = 44;
    const int nc = blockIdx.x;
    const int n = nc >> 8, c = nc & 255;
    const float mu = stats[2 * n], rstd = stats[2 * n + 1];
    const float gsc = a_gn_w[c] * rstd;
    const float gsh = a_gn_b[c] - mu * gsc;
    if (t < 49) comb[t] = a_dw7[c * 49 + t];
    __syncthreads();
    if (t < 9) comb[(t / 3) * 21 + (t % 3) * 3] += a_dw3[c * 9 + t];
    const float* xc = xa + (size_t)nc * AHW;
    for (int idx = t; idx < TH * TW; idx += 256) {
      int th = idx / TW, tw = idx - th * TW;
      int h = th - 3, w = tw - 3;
      float val = 0.f;
      if (h >= 0 && h < 32 && w >= 0 && w < 32) val = xc[h * 32 + w] * gsc + gsh;
      tile[th * TWP + tw] = val;
    }
    __syncthreads();
    if (t < 128) {
      const int rg = t >> 3, cq = t & 7;
      const int r0 = rg * 2, w0 = cq * 4;
      float acc[2][4];
      #pragma unroll
      for (int r = 0; r < 2; ++r)
        #pragma unroll
        for (int j = 0; j < 4; ++j) acc[r][j] = 0.f;
      #pragma unroll
      for (int i = 0; i < 8; ++i) {
        const float* row = &tile[(r0 + i) * TWP + w0];
        float4 ra = *(const float4*)(row);
        float4 rb = *(const float4*)(row + 4);
        float2 rc = *(const float2*)(row + 8);
        float rr[10] = {ra.x, ra.y, ra.z, ra.w, rb.x, rb.y, rb.z, rb.w, rc.x, rc.y};
        #pragma unroll
        for (int ky = 0; ky < 7; ++ky) {
          int orow = i - ky;
          if (orow >= 0 && orow < 2) {
            #pragma unroll
            for (int kx = 0; kx < 7; ++kx) {
              float wg = comb[ky * 7 + kx];
              #pragma unroll
              for (int j = 0; j < 4; ++j)
                acc[orow][j] = fmaf(rr[kx + j], wg, acc[orow][j]);
            }
          }
        }
      }
      u16* oc = outa + (size_t)nc * AHW;
      #pragma unroll
      for (int r = 0; r < 2; ++r) {
        u16x4 res = {f2b(acc[r][0]), f2b(acc[r][1]), f2b(acc[r][2]), f2b(acc[r][3])};
        *(u16x4*)&oc[(r0 + r) * 32 + w0] = res;
      }
    }
  } else {
    // ----- v-path: vector staging + quad XOR swizzle (R7 verified) --------
    const int nc = blockIdx.x - 1024;
    const int n = nc >> 8, c = nc & 255;
    const float mu = stats[8 + 2 * n], rstd = stats[8 + 2 * n + 1];
    const float gsc = v_gn_w[c] * rstd;
    const float gsh = v_gn_b[c] - mu * gsc;
    if (t < 49) comb[t] = v_dw7[c * 49 + t];
    __syncthreads();
    if (t < 9) comb[(t / 3) * 21 + (t % 3) * 3] += v_dw3[c * 9 + t];
    const float* xc = xv + (size_t)nc * VHW;
    if (t < 208) {   // zero pads
      int row, q;
      if (t < 96) { int ri = t >> 4; row = (ri < 3) ? ri : ri + 56; q = t & 15; }
      else        { int r = t - 96; row = 3 + (r >> 1); q = (r & 1) ? 15 : 0; }
      int qz = q ^ (row & 7);
      f32x4 z = {0.f, 0.f, 0.f, 0.f};
      *(f32x4*)&tile[row * 64 + qz * 4] = z;
    }
    #pragma unroll
    for (int it = 0; it < 4; ++it) {   // 784 aligned float4 stages
      int idx = t + it * 256;
      if (idx < 784) {
        int row = idx / 14, q = idx - row * 14;
        float4 v = *(const float4*)(xc + row * VW_ + q * 4);
        int trow = row + 3;
        int tq = (q + 1) ^ (trow & 7);
        f32x4 sv = {v.x * gsc + gsh, v.y * gsc + gsh,
                    v.z * gsc + gsh, v.w * gsc + gsh};
        *(f32x4*)&tile[trow * 64 + tq * 4] = sv;
      }
    }
    __syncthreads();
    if (t < 196) {
      const int rg = t / 14, cq = t - rg * 14;
      const int r0 = rg * 4;
      float acc[4][4];
      #pragma unroll
      for (int r = 0; r < 4; ++r)
        #pragma unroll
        for (int j = 0; j < 4; ++j) acc[r][j] = 0.f;
      #pragma unroll
      for (int i = 0; i < 10; ++i) {
        int trow = r0 + i;
        const float* rowb = &tile[trow * 64];
        int rz = trow & 7;
        float rr[12];
        #pragma unroll
        for (int k = 0; k < 3; ++k) {
          int qk = (cq + k) ^ rz;
          f32x4 rv = *(const f32x4*)(rowb + qk * 4);
          rr[4 * k + 0] = rv[0]; rr[4 * k + 1] = rv[1];
          rr[4 * k + 2] = rv[2]; rr[4 * k + 3] = rv[3];
        }
        #pragma unroll
        for (int ky = 0; ky < 7; ++ky) {
          int orow = i - ky;
          if (orow >= 0 && orow < 4) {
            #pragma unroll
            for (int kx = 0; kx < 7; ++kx) {
              float wg = comb[ky * 7 + kx];
              #pragma unroll
              for (int j = 0; j < 4; ++j)
                acc[orow][j] = fmaf(rr[j + kx + 1], wg, acc[orow][j]);
            }
          }
        }
      }
      u16* oc = outv + (size_t)nc * VHW;
      #pragma unroll
      for (int r = 0; r < 4; ++r) {
        u16x4 res = {f2b(acc[r][0]), f2b(acc[r][1]), f2b(acc[r][2]), f2b(acc[r][3])};
        *(u16x4*)&oc[(r0 + r) * VW_ + cq * 4] = res;
      }
    }
  }
}

// ---------------- merged pointwise MFMA GEMM, c-major X, CP output ---------
// D[o][p] = act(bias[o] + sum_k W[o][k] * X[k][p]);  X is [S][256][HW] bf16
// (dwconv-native).  Staging transposes in-register (R4/R5-verified path).
template<int ACT, int NBA, int PTA, int PTV>
__global__ __launch_bounds__(256) void mfma_pw2(
    const u16* __restrict__ Xa, const u16* __restrict__ Wa,
    const float* __restrict__ ba, u16* __restrict__ outa_cp,
    const u16* __restrict__ Xv, const u16* __restrict__ Wv,
    const float* __restrict__ bv, u16* __restrict__ outv_cp)
{
  __shared__ __align__(16) char smem[256 * 72 * 2 + 64 * 68 * 2];   // 44.5 KiB
  u16* Wl = (u16*)smem;                 // [256][72]
  u16* Xl = (u16*)smem + 256 * 72;      // [64][68]  (p-major after transpose)
  float* Tt = (float*)smem;             // [128][64] f32 epilogue transpose
  const int t = threadIdx.x;
  const int lane = t & 63, wid = t >> 6;
  const int g = lane >> 4, lr = lane & 15;
  int bid = blockIdx.x;
  const u16 *X, *W; const float* bias; u16* out_cp; int HW, px, s;
  if (bid < NBA) {
    X = Xa; W = Wa; bias = ba; out_cp = outa_cp;
    HW = PTA * 64; px = bid % PTA; s = bid / PTA;
  } else {
    bid -= NBA;
    X = Xv; W = Wv; bias = bv; out_cp = outv_cp;
    HW = PTV * 64; px = bid % PTV; s = bid / PTV;
  }
  const int p0 = px * 64;
  const u16* Xs = X + (size_t)s * 256 * HW + p0;
  const int cg = t >> 4, pg = t & 15;   // staging: 64 channels x 64 p
  f32x4 acc[4][4] = {};
  u16x8 stw[8];
  u16x4 stc[4];
  #pragma unroll
  for (int it = 0; it < 8; ++it) {
    int slot = it * 256 + t, row = slot >> 3, ch = slot & 7;
    stw[it] = *(const u16x8*)(W + row * 256 + ch * 8);
  }
  #pragma unroll
  for (int cc = 0; cc < 4; ++cc)
    stc[cc] = *(const u16x4*)(Xs + (size_t)(cg * 4 + cc) * HW + pg * 4);
  for (int kt = 0; kt < 4; ++kt) {
    __syncthreads();
    #pragma unroll
    for (int it = 0; it < 8; ++it) {
      int slot = it * 256 + t, row = slot >> 3, ch = slot & 7;
      *(u16x8*)&Wl[row * 72 + ch * 8] = stw[it];
    }
    #pragma unroll
    for (int pp = 0; pp < 4; ++pp) {    // register transpose -> [p][c] LDS
      u16x4 vv = {stc[0][pp], stc[1][pp], stc[2][pp], stc[3][pp]};
      *(u16x4*)&Xl[(pg * 4 + pp) * 68 + cg * 4] = vv;
    }
    __syncthreads();
    if (kt < 3) {
      const int k1 = (kt + 1) * 64;
      #pragma unroll
      for (int it = 0; it < 8; ++it) {
        int slot = it * 256 + t, row = slot >> 3, ch = slot & 7;
        stw[it] = *(const u16x8*)(W + row * 256 + k1 + ch * 8);
      }
      #pragma unroll
      for (int cc = 0; cc < 4; ++cc)
        stc[cc] = *(const u16x4*)(Xs + (size_t)(k1 + cg * 4 + cc) * HW + pg * 4);
    }
    #pragma unroll
    for (int ks = 0; ks < 2; ++ks) {
      s16x8 af[4], bf[4];
      #pragma unroll
      for (int m = 0; m < 4; ++m) {
        int row = wid * 64 + m * 16 + lr;
        af[m] = *(const s16x8*)&Wl[row * 72 + ks * 32 + g * 8];
      }
      #pragma unroll
      for (int n = 0; n < 4; ++n) {
        int row = n * 16 + lr;
        bf[n] = *(const s16x8*)&Xl[row * 68 + ks * 32 + g * 8];
      }
      #pragma unroll
      for (int m = 0; m < 4; ++m)
        #pragma unroll
        for (int n = 0; n < 4; ++n)
          acc[m][n] = __builtin_amdgcn_mfma_f32_16x16x32_bf16(af[m], bf[n], acc[m][n], 0, 0, 0);
    }
  }
  __syncthreads();
  #pragma unroll
  for (int m = 0; m < 4; ++m) {
    int ob = wid * 64 + m * 16 + g * 4;
    float4 b4 = *(const float4*)&bias[ob];
    float bb[4] = {b4.x, b4.y, b4.z, b4.w};
    #pragma unroll
    for (int n = 0; n < 4; ++n)
      #pragma unroll
      for (int r = 0; r < 4; ++r) {
        float y = acc[m][n][r] + bb[r];
        acc[m][n][r] = (ACT == 0) ? gelu_f(y) : sigmoid_f(y);
      }
  }
  // CP epilogue: LDS f32 transpose -> coalesced bf16 [c][p] stores
  #pragma unroll
  for (int ho = 0; ho < 2; ++ho) {
    __syncthreads();
    if ((wid >> 1) == ho) {
      #pragma unroll
      for (int m = 0; m < 4; ++m) {
        int ol = (wid & 1) * 64 + m * 16 + g * 4;
        #pragma unroll
        for (int n = 0; n < 4; ++n) {
          int p = n * 16 + lr, q = p >> 2;
          #pragma unroll
          for (int r = 0; r < 4; ++r) {
            int orow = ol + r;
            Tt[orow * 64 + ((q ^ (orow & 15)) << 2) + (p & 3)] = acc[m][n][r];
          }
        }
      }
    }
    __syncthreads();
    #pragma unroll
    for (int it = 0; it < 8; ++it) {
      int slot = it * 256 + t;
      int ol = slot >> 4, q = slot & 15;
      float4 v4 = *(const float4*)&Tt[ol * 64 + ((q ^ (ol & 15)) << 2)];
      u16x4 pk = {f2b(v4.x), f2b(v4.y), f2b(v4.z), f2b(v4.w)};
      int o = ho * 128 + ol;
      *(u16x4*)(out_cp + ((size_t)s * 256 + o) * HW + p0 + q * 4) = pk;
    }
  }
}

// -------- merged T-mean pool + bilinear, CP in / CP out --------------------
// blocks 0..1023: pool (b,c); blocks 1024..2047: bilinear (b,c)
__global__ __launch_bounds__(256) void pool_bilin_cp(
    const u16* __restrict__ vf_cp, u16* __restrict__ vfa_cp,
    const u16* __restrict__ af_cp, u16* __restrict__ afv_cp)
{
  const int t = threadIdx.x;
  int bid = blockIdx.x;
  if (bid < 1024) {
    int b = bid >> 8, c = bid & 255;
    u16* dst = vfa_cp + ((size_t)(b * 256 + c) << 10);
    #pragma unroll
    for (int k = 0; k < 4; ++k) {
      int idx = t + k * 256;               // output pixel in 32x32
      int oh = idx >> 5, ow = idx & 31;
      int sh = (oh * VH_) >> 5, eh = ((oh + 1) * VH_ + 31) >> 5;
      int sw = (ow * VW_) >> 5, ew = ((ow + 1) * VW_ + 31) >> 5;
      float acc = 0.f;
      for (int tt = 0; tt < T_; ++tt) {
        const u16* base = vf_cp + ((size_t)((b * T_ + tt) * 256 + c)) * VHW;
        for (int ih = sh; ih < eh; ++ih)
          for (int iw = sw; iw < ew; ++iw)
            acc += b2f(base[ih * VW_ + iw]);
      }
      dst[idx] = f2b(acc / (float)(T_ * (eh - sh) * (ew - sw)));
    }
  } else {
    bid -= 1024;
    int b = bid >> 8, c = bid & 255;
    const u16* base = af_cp + ((size_t)(b * 256 + c) << 10);
    u16* dst = afv_cp + (size_t)(b * 256 + c) * VHW;
    const float sc = (float)AH_ / (float)VH_;
    for (int k = 0; k < 13; ++k) {
      int idx = t + k * 256;
      if (idx < VHW) {
        int oh = idx / VW_, ow = idx - oh * VW_;
        float srh = fminf(fmaxf((oh + 0.5f) * sc - 0.5f, 0.f), (float)(AH_ - 1));
        float srw = fminf(fmaxf((ow + 0.5f) * sc - 0.5f, 0.f), (float)(AW_ - 1));
        int h0 = (int)srh, w0 = (int)srw;
        int h1 = min(h0 + 1, AH_ - 1), w1 = min(w0 + 1, AW_ - 1);
        float fh = srh - (float)h0, fw = srw - (float)w0;
        float v00 = b2f(base[h0 * AW_ + w0]), v01 = b2f(base[h0 * AW_ + w1]);
        float v10 = b2f(base[h1 * AW_ + w0]), v11 = b2f(base[h1 * AW_ + w1]);
        float top = v00 + (v01 - v00) * fw;
        float bot = v10 + (v11 - v10) * fw;
        dst[idx] = f2b(top + (bot - top) * fh);
      }
    }
  }
}

// -------- merged residual gates: a (blocks 0..511) + v ---------------------
__global__ __launch_bounds__(256) void final_av(
    const float* __restrict__ a, const u16* __restrict__ afcp,
    const u16* __restrict__ gacp, const float* __restrict__ sa,
    const float* __restrict__ v, const u16* __restrict__ vfcp,
    const u16* __restrict__ gvcp, const float* __restrict__ sv,
    float* __restrict__ out)
{
  int bid = blockIdx.x;
  if (bid < 512) {
    size_t i = ((size_t)bid * 256 + threadIdx.x) * 8;
    float s = sa[0];
    float4 a0 = *(const float4*)(a + i), a1 = *(const float4*)(a + i + 4);
    u16x8 f = *(const u16x8*)(afcp + i);
    u16x8 gg = *(const u16x8*)(gacp + i);
    float4 o0 = {a0.x + s * b2f(f[0]) * b2f(gg[0]), a0.y + s * b2f(f[1]) * b2f(gg[1]),
                 a0.z + s * b2f(f[2]) * b2f(gg[2]), a0.w + s * b2f(f[3]) * b2f(gg[3])};
    float4 o1 = {a1.x + s * b2f(f[4]) * b2f(gg[4]), a1.y + s * b2f(f[5]) * b2f(gg[5]),
                 a1.z + s * b2f(f[6]) * b2f(gg[6]), a1.w + s * b2f(f[7]) * b2f(gg[7])};
    *(float4*)(out + i) = o0;
    *(float4*)(out + i + 4) = o1;
  } else {
    size_t i = ((size_t)(bid - 512) * 256 + threadIdx.x) * 8;
    const size_t PER = (size_t)C_ * VHW;
    int bt = (int)(i / PER);
    size_t rem = i - (size_t)bt * PER;
    const u16* gp = gvcp + (size_t)(bt >> 2) * PER + rem;
    float s = sv[0];
    float4 v0 = *(const float4*)(v + i), v1 = *(const float4*)(v + i + 4);
    u16x8 f = *(const u16x8*)(vfcp + i);
    u16x8 gg = *(const u16x8*)gp;
    float4 o0 = {v0.x + s * b2f(f[0]) * b2f(gg[0]), v0.y + s * b2f(f[1]) * b2f(gg[1]),
                 v0.z + s * b2f(f[2]) * b2f(gg[2]), v0.w + s * b2f(f[3]) * b2f(gg[3])};
    float4 o1 = {v1.x + s * b2f(f[4]) * b2f(gg[4]), v1.y + s * b2f(f[5]) * b2f(gg[5]),
                 v1.z + s * b2f(f[6]) * b2f(gg[6]), v1.w + s * b2f(f[7]) * b2f(gg[7])};
    float* ov = out + NA_;
    *(float4*)(ov + i) = o0;
    *(float4*)(ov + i + 4) = o1;
  }
}

// ---------------------------------------------------------------------------
extern "C" void kernel_launch(void* const* d_in, const int* in_sizes, int n_in,
                              void* d_out, int out_size, void* d_ws, size_t ws_size,
                              hipStream_t stream)
{
  const float* a        = (const float*)d_in[0];
  const float* v        = (const float*)d_in[1];
  const float* a_gn_w   = (const float*)d_in[2];
  const float* a_gn_b   = (const float*)d_in[3];
  const float* a_dw7    = (const float*)d_in[4];
  const float* a_dw3    = (const float*)d_in[5];
  const float* a_pw_w   = (const float*)d_in[6];
  const float* a_pw_b   = (const float*)d_in[7];
  const float* v_gn_w   = (const float*)d_in[8];
  const float* v_gn_b   = (const float*)d_in[9];
  const float* v_dw7    = (const float*)d_in[10];
  const float* v_dw3    = (const float*)d_in[11];
  const float* v_pw_w   = (const float*)d_in[12];
  const float* v_pw_b   = (const float*)d_in[13];
  const float* gate_a_w = (const float*)d_in[14];
  const float* gate_a_b = (const float*)d_in[15];
  const float* gate_v_w = (const float*)d_in[16];
  const float* gate_v_b = (const float*)d_in[17];
  const float* scale_a  = (const float*)d_in[18];
  const float* scale_v  = (const float*)d_in[19];
  float* out = (float*)d_out;
  char* wsb = (char*)d_ws;

  const size_t SZ_V  = (size_t)NV_ * 2;     // 25.7 MB
  const size_t SZ_AV = (size_t)NAV_ * 2;    //  6.4 MB
  const size_t SZ_A  = (size_t)NA_ * 2;     //  2.1 MB
  // region 0: dwv_b (dead after GELU GEMM) -> afv + gatev_cp aliases
  u16* dwv_b    = (u16*)(wsb + 0);
  u16* afv      = (u16*)(wsb + 0);
  u16* gatev_cp = (u16*)(wsb + SZ_AV);
  u16* vfeat_cp = (u16*)(wsb + SZ_V);
  u16* dwa_b    = (u16*)(wsb + 2 * SZ_V);
  u16* afeat_cp = (u16*)(wsb + 2 * SZ_V + SZ_A);
  u16* vfa      = (u16*)(wsb + 2 * SZ_V + 2 * SZ_A);
  u16* gatea_cp = (u16*)(wsb + 2 * SZ_V + 3 * SZ_A);
  u16* w_bf     = (u16*)(wsb + 2 * SZ_V + 4 * SZ_A);   // 4 * 65536 bf16
  float* pf     = (float*)(wsb + 2 * SZ_V + 4 * SZ_A + 4 * 65536 * 2);
  float* part   = pf;                                  // 5120
  float* stats  = pf + 5120;                           // 40
  u16* wA = w_bf, *wV = w_bf + 65536, *wGA = w_bf + 131072, *wGV = w_bf + 196608;

  // 1. weights -> bf16
  cvt_bf16_4<<<128, 256, 0, stream>>>(a_pw_w, v_pw_w, gate_a_w, gate_v_w, w_bf);

  // 2. GroupNorm stats
  gn_reduce1m<<<dim3(128, 20), 256, 0, stream>>>(a, v, part);
  gn_reduce2m<<<20, 128, 0, stream>>>(part, stats);

  // 3. merged GN + dwconv -> [c][p] bf16 (a: 1024, v: 4096 blocks)
  gn_dwconv_all<<<5120, 256, 0, stream>>>(a, v, stats,
      a_gn_w, a_gn_b, a_dw7, a_dw3, v_gn_w, v_gn_b, v_dw7, v_dw3, dwa_b, dwv_b);

  // 4. merged pwconv + GELU, c-major in, CP out (a: 64, v: 784 blocks)
  mfma_pw2<0, 64, 16, 49><<<848, 256, 0, stream>>>(
      dwa_b, wA, a_pw_b, afeat_cp,
      dwv_b, wV, v_pw_b, vfeat_cp);

  // 5. merged pool (1024) + bilinear (1024), CP in/out
  pool_bilin_cp<<<2048, 256, 0, stream>>>(vfeat_cp, vfa, afeat_cp, afv);

  // 6. merged gate GEMMs: gate_a (64) + gate_v (196), sigmoid, CP out
  mfma_pw2<1, 64, 16, 49><<<260, 256, 0, stream>>>(
      vfa, wGA, gate_a_b, gatea_cp,
      afv, wGV, gate_v_b, gatev_cp);

  // 7. merged residual gates (a: 512, v: 6272)
  final_av<<<6784, 256, 0, stream>>>(a, afeat_cp, gatea_cp, scale_a,
                                     v, vfeat_cp, gatev_cp, scale_v, out);
}

// Round 11
// 156.968 us; speedup vs baseline: 1.0175x; 1.0175x over previous
//
#include <hip/hip_runtime.h>
#include <math.h>

#define C_   256
#define B_   4
#define T_   4
#define AH_  32
#define AW_  32
#define VH_  56
#define VW_  56
#define AHW  (AH_*AW_)          // 1024
#define VHW  (VH_*VW_)          // 3136
#define NA_  (B_*C_*AHW)        // 1,048,576
#define NV_  (B_*T_*C_*VHW)     // 12,845,056
#define NAV_ (B_*C_*VHW)        // 3,211,264

typedef unsigned short u16;
typedef short s16x8 __attribute__((ext_vector_type(8)));
typedef unsigned short u16x8 __attribute__((ext_vector_type(8)));
typedef unsigned short u16x4 __attribute__((ext_vector_type(4)));
typedef float f32x4 __attribute__((ext_vector_type(4)));

__device__ __forceinline__ u16 f2b(float f) {            // fp32 -> bf16 RNE
  unsigned u = __float_as_uint(f);
  u += 0x7FFFu + ((u >> 16) & 1u);
  return (u16)(u >> 16);
}
__device__ __forceinline__ float b2f(u16 h) {
  return __uint_as_float((unsigned)h << 16);
}
// tanh-form GELU: |err| vs exact ~3e-4
__device__ __forceinline__ float gelu_f(float x) {
  float x2 = x * x;
  float e = __expf(x * (-1.5957691216f - 0.0713548162f * x2));
  return x * __builtin_amdgcn_rcpf(1.f + e);
}
__device__ __forceinline__ float sigmoid_f(float x) {
  return __builtin_amdgcn_rcpf(1.f + __expf(-x));
}

// ---------------- fp32 -> bf16 convert, all 4 weight matrices --------------
__global__ __launch_bounds__(256) void cvt_bf16_4(
    const float* __restrict__ s0, const float* __restrict__ s1,
    const float* __restrict__ s2, const float* __restrict__ s3,
    u16* __restrict__ dst)
{
  int g = blockIdx.x >> 5;
  const float* src = (g == 0) ? s0 : (g == 1) ? s1 : (g == 2) ? s2 : s3;
  size_t i = ((size_t)(blockIdx.x & 31) * 256 + threadIdx.x) * 8;
  float4 v0 = *(const float4*)(src + i);
  float4 v1 = *(const float4*)(src + i + 4);
  u16x8 o = {f2b(v0.x), f2b(v0.y), f2b(v0.z), f2b(v0.w),
             f2b(v1.x), f2b(v1.y), f2b(v1.z), f2b(v1.w)};
  *(u16x8*)(dst + (size_t)g * 65536 + i) = o;
}

// ---------------- GroupNorm(1,C) stats: merged a+v, 2-stage ----------------
__global__ __launch_bounds__(256) void gn_reduce1m(
    const float* __restrict__ a, const float* __restrict__ v,
    float* __restrict__ part)
{
  int samp = blockIdx.y, chunk = blockIdx.x;
  const float* x; int per;
  if (samp < 4) { x = a + (size_t)samp * (C_ * AHW); per = (C_ * AHW / 4) / 128; }
  else          { x = v + (size_t)(samp - 4) * (C_ * VHW); per = (C_ * VHW / 4) / 128; }
  const float4* xb = (const float4*)x + (size_t)chunk * per;
  float s = 0.f, s2 = 0.f;
  for (int i = threadIdx.x; i < per; i += 256) {
    float4 q = xb[i];
    s  += q.x + q.y + q.z + q.w;
    s2 += q.x*q.x + q.y*q.y + q.z*q.z + q.w*q.w;
  }
  __shared__ float sh1[256], sh2[256];
  sh1[threadIdx.x] = s; sh2[threadIdx.x] = s2;
  __syncthreads();
  for (int st = 128; st > 0; st >>= 1) {
    if (threadIdx.x < st) {
      sh1[threadIdx.x] += sh1[threadIdx.x + st];
      sh2[threadIdx.x] += sh2[threadIdx.x + st];
    }
    __syncthreads();
  }
  if (threadIdx.x == 0) {
    part[(samp * 128 + chunk) * 2 + 0] = sh1[0];
    part[(samp * 128 + chunk) * 2 + 1] = sh2[0];
  }
}

__global__ __launch_bounds__(128) void gn_reduce2m(
    const float* __restrict__ part, float* __restrict__ stats)
{
  int samp = blockIdx.x;
  int t = threadIdx.x;
  __shared__ float sh1[128], sh2[128];
  sh1[t] = part[(samp * 128 + t) * 2 + 0];
  sh2[t] = part[(samp * 128 + t) * 2 + 1];
  __syncthreads();
  for (int st = 64; st > 0; st >>= 1) {
    if (t < st) { sh1[t] += sh1[t + st]; sh2[t] += sh2[t + st]; }
    __syncthreads();
  }
  if (t == 0) {
    float invN = (samp < 4) ? 1.f / (float)(C_ * AHW) : 1.f / (float)(C_ * VHW);
    float mu  = sh1[0] * invN;
    float var = sh2[0] * invN - mu * mu;
    stats[samp * 2 + 0] = mu;
    stats[samp * 2 + 1] = rsqrtf(var + 1e-5f);
  }
}

// ---------------- merged GN+dwconv: a-path (blocks 0..1023) + v-path -------
__global__ __launch_bounds__(256) void gn_dwconv_all(
    const float* __restrict__ xa, const float* __restrict__ xv,
    const float* __restrict__ stats,
    const float* __restrict__ a_gn_w, const float* __restrict__ a_gn_b,
    const float* __restrict__ a_dw7, const float* __restrict__ a_dw3,
    const float* __restrict__ v_gn_w, const float* __restrict__ v_gn_b,
    const float* __restrict__ v_dw7, const float* __restrict__ v_dw3,
    u16* __restrict__ outa, u16* __restrict__ outv)
{
  __shared__ float tile[62 * 64];
  __shared__ float comb[49];
  const int t = threadIdx.x;
  if (blockIdx.x < 1024) {
    constexpr int TH = 38, TW = 38, TWP = 44;
    const int nc = blockIdx.x;
    const int n = nc >> 8, c = nc & 255;
    const float mu = stats[2 * n], rstd = stats[2 * n + 1];
    const float gsc = a_gn_w[c] * rstd;
    const float gsh = a_gn_b[c] - mu * gsc;
    if (t < 49) comb[t] = a_dw7[c * 49 + t];
    __syncthreads();
    if (t < 9) comb[(t / 3) * 21 + (t % 3) * 3] += a_dw3[c * 9 + t];
    const float* xc = xa + (size_t)nc * AHW;
    for (int idx = t; idx < TH * TW; idx += 256) {
      int th = idx / TW, tw = idx - th * TW;
      int h = th - 3, w = tw - 3;
      float val = 0.f;
      if (h >= 0 && h < 32 && w >= 0 && w < 32) val = xc[h * 32 + w] * gsc + gsh;
      tile[th * TWP + tw] = val;
    }
    __syncthreads();
    if (t < 128) {
      const int rg = t >> 3, cq = t & 7;
      const int r0 = rg * 2, w0 = cq * 4;
      float acc[2][4];
      #pragma unroll
      for (int r = 0; r < 2; ++r)
        #pragma unroll
        for (int j = 0; j < 4; ++j) acc[r][j] = 0.f;
      #pragma unroll
      for (int i = 0; i < 8; ++i) {
        const float* row = &tile[(r0 + i) * TWP + w0];
        float4 ra = *(const float4*)(row);
        float4 rb = *(const float4*)(row + 4);
        float2 rc = *(const float2*)(row + 8);
        float rr[10] = {ra.x, ra.y, ra.z, ra.w, rb.x, rb.y, rb.z, rb.w, rc.x, rc.y};
        #pragma unroll
        for (int ky = 0; ky < 7; ++ky) {
          int orow = i - ky;
          if (orow >= 0 && orow < 2) {
            #pragma unroll
            for (int kx = 0; kx < 7; ++kx) {
              float wg = comb[ky * 7 + kx];
              #pragma unroll
              for (int j = 0; j < 4; ++j)
                acc[orow][j] = fmaf(rr[kx + j], wg, acc[orow][j]);
            }
          }
        }
      }
      u16* oc = outa + (size_t)nc * AHW;
      #pragma unroll
      for (int r = 0; r < 2; ++r) {
        u16x4 res = {f2b(acc[r][0]), f2b(acc[r][1]), f2b(acc[r][2]), f2b(acc[r][3])};
        *(u16x4*)&oc[(r0 + r) * 32 + w0] = res;
      }
    }
  } else {
    const int nc = blockIdx.x - 1024;
    const int n = nc >> 8, c = nc & 255;
    const float mu = stats[8 + 2 * n], rstd = stats[8 + 2 * n + 1];
    const float gsc = v_gn_w[c] * rstd;
    const float gsh = v_gn_b[c] - mu * gsc;
    if (t < 49) comb[t] = v_dw7[c * 49 + t];
    __syncthreads();
    if (t < 9) comb[(t / 3) * 21 + (t % 3) * 3] += v_dw3[c * 9 + t];
    const float* xc = xv + (size_t)nc * VHW;
    if (t < 208) {   // zero pads
      int row, q;
      if (t < 96) { int ri = t >> 4; row = (ri < 3) ? ri : ri + 56; q = t & 15; }
      else        { int r = t - 96; row = 3 + (r >> 1); q = (r & 1) ? 15 : 0; }
      int qz = q ^ (row & 7);
      f32x4 z = {0.f, 0.f, 0.f, 0.f};
      *(f32x4*)&tile[row * 64 + qz * 4] = z;
    }
    #pragma unroll
    for (int it = 0; it < 4; ++it) {
      int idx = t + it * 256;
      if (idx < 784) {
        int row = idx / 14, q = idx - row * 14;
        float4 v = *(const float4*)(xc + row * VW_ + q * 4);
        int trow = row + 3;
        int tq = (q + 1) ^ (trow & 7);
        f32x4 sv = {v.x * gsc + gsh, v.y * gsc + gsh,
                    v.z * gsc + gsh, v.w * gsc + gsh};
        *(f32x4*)&tile[trow * 64 + tq * 4] = sv;
      }
    }
    __syncthreads();
    if (t < 196) {
      const int rg = t / 14, cq = t - rg * 14;
      const int r0 = rg * 4;
      float acc[4][4];
      #pragma unroll
      for (int r = 0; r < 4; ++r)
        #pragma unroll
        for (int j = 0; j < 4; ++j) acc[r][j] = 0.f;
      #pragma unroll
      for (int i = 0; i < 10; ++i) {
        int trow = r0 + i;
        const float* rowb = &tile[trow * 64];
        int rz = trow & 7;
        float rr[12];
        #pragma unroll
        for (int k = 0; k < 3; ++k) {
          int qk = (cq + k) ^ rz;
          f32x4 rv = *(const f32x4*)(rowb + qk * 4);
          rr[4 * k + 0] = rv[0]; rr[4 * k + 1] = rv[1];
          rr[4 * k + 2] = rv[2]; rr[4 * k + 3] = rv[3];
        }
        #pragma unroll
        for (int ky = 0; ky < 7; ++ky) {
          int orow = i - ky;
          if (orow >= 0 && orow < 4) {
            #pragma unroll
            for (int kx = 0; kx < 7; ++kx) {
              float wg = comb[ky * 7 + kx];
              #pragma unroll
              for (int j = 0; j < 4; ++j)
                acc[orow][j] = fmaf(rr[j + kx + 1], wg, acc[orow][j]);
            }
          }
        }
      }
      u16* oc = outv + (size_t)nc * VHW;
      #pragma unroll
      for (int r = 0; r < 4; ++r) {
        u16x4 res = {f2b(acc[r][0]), f2b(acc[r][1]), f2b(acc[r][2]), f2b(acc[r][3])};
        *(u16x4*)&oc[(r0 + r) * VW_ + cq * 4] = res;
      }
    }
  }
}

// -------- merged bf16 transpose [S][256][HW] -> [S][HW][256], a+v ----------
__global__ __launch_bounds__(256) void transpose_all(
    const u16* __restrict__ ina, u16* __restrict__ outa,
    const u16* __restrict__ inv, u16* __restrict__ outv)
{
  __shared__ u16 tile[64 * 68];
  const int t = threadIdx.x;
  int bid = blockIdx.x;
  const u16* in; u16* outp; int HW, PT;
  if (bid < 256) { in = ina; outp = outa; HW = AHW; PT = 16; }
  else           { bid -= 256; in = inv; outp = outv; HW = VHW; PT = 49; }
  int px = bid % PT; int rem = bid / PT;
  int cy = rem & 3, s = rem >> 2;
  const int p0 = px * 64, c0 = cy * 64;
  const u16* src = in + ((size_t)s * 256 + c0) * HW + p0;
  #pragma unroll
  for (int it = 0; it < 2; ++it) {
    int slot = it * 256 + t;
    int cr = slot >> 3, ch = slot & 7;
    u16x8 v = *(const u16x8*)(src + (size_t)cr * HW + ch * 8);
    u16x4 lo = {v[0], v[1], v[2], v[3]}, hi = {v[4], v[5], v[6], v[7]};
    *(u16x4*)&tile[cr * 68 + ch * 8] = lo;
    *(u16x4*)&tile[cr * 68 + ch * 8 + 4] = hi;
  }
  __syncthreads();
  int pr = t >> 2, ch = t & 3;
  u16* dst = outp + ((size_t)s * HW + p0 + pr) * 256 + c0;
  #pragma unroll
  for (int jj = 0; jj < 2; ++jj) {
    int cb = ch * 8 + jj * 32;
    u16x8 o;
    #pragma unroll
    for (int j = 0; j < 8; ++j) o[j] = tile[(cb + j) * 68 + pr];
    *(u16x8*)(dst + cb) = o;
  }
}

// ---------------- p-major MFMA GEMM (R8 staging), CP-only output -----------
template<int ACT, int NBA, int PTA, int PTV>
__global__ __launch_bounds__(256) void mfma_pw_pm(
    const u16* __restrict__ Xa, const u16* __restrict__ Wa,
    const float* __restrict__ ba, u16* __restrict__ outa_cp,
    const u16* __restrict__ Xv, const u16* __restrict__ Wv,
    const float* __restrict__ bv, u16* __restrict__ outv_cp)
{
  __shared__ __align__(16) char smem[(256 * 72 + 64 * 72) * 2];   // 45 KiB
  u16* Wl = (u16*)smem;
  u16* Xl = (u16*)smem + 256 * 72;
  float* Tt = (float*)smem;
  const int t = threadIdx.x;
  const int lane = t & 63, wid = t >> 6;
  const int g = lane >> 4, lr = lane & 15;
  int bid = blockIdx.x;
  const u16 *X, *W; const float* bias; u16* out_cp; int HW, px, s;
  if (bid < NBA) {
    X = Xa; W = Wa; bias = ba; out_cp = outa_cp;
    HW = PTA * 64; px = bid % PTA; s = bid / PTA;
  } else {
    bid -= NBA;
    X = Xv; W = Wv; bias = bv; out_cp = outv_cp;
    HW = PTV * 64; px = bid % PTV; s = bid / PTV;
  }
  const int p0 = px * 64;
  const u16* Xs = X + ((size_t)s * HW + p0) * 256;
  f32x4 acc[4][4] = {};
  u16x8 stw[8], stx[2];
  #pragma unroll
  for (int it = 0; it < 8; ++it) {
    int slot = it * 256 + t, row = slot >> 3, ch = slot & 7;
    stw[it] = *(const u16x8*)(W + row * 256 + ch * 8);
  }
  #pragma unroll
  for (int it = 0; it < 2; ++it) {
    int slot = it * 256 + t, row = slot >> 3, ch = slot & 7;
    stx[it] = *(const u16x8*)(Xs + (size_t)row * 256 + ch * 8);
  }
  for (int kt = 0; kt < 4; ++kt) {
    __syncthreads();
    #pragma unroll
    for (int it = 0; it < 8; ++it) {
      int slot = it * 256 + t, row = slot >> 3, ch = slot & 7;
      *(u16x8*)&Wl[row * 72 + ch * 8] = stw[it];
    }
    #pragma unroll
    for (int it = 0; it < 2; ++it) {
      int slot = it * 256 + t, row = slot >> 3, ch = slot & 7;
      *(u16x8*)&Xl[row * 72 + ch * 8] = stx[it];
    }
    __syncthreads();
    if (kt < 3) {
      const int k1 = (kt + 1) * 64;
      #pragma unroll
      for (int it = 0; it < 8; ++it) {
        int slot = it * 256 + t, row = slot >> 3, ch = slot & 7;
        stw[it] = *(const u16x8*)(W + row * 256 + k1 + ch * 8);
      }
      #pragma unroll
      for (int it = 0; it < 2; ++it) {
        int slot = it * 256 + t, row = slot >> 3, ch = slot & 7;
        stx[it] = *(const u16x8*)(Xs + (size_t)row * 256 + k1 + ch * 8);
      }
    }
    #pragma unroll
    for (int ks = 0; ks < 2; ++ks) {
      s16x8 af[4], bf[4];
      #pragma unroll
      for (int m = 0; m < 4; ++m) {
        int row = wid * 64 + m * 16 + lr;
        af[m] = *(const s16x8*)&Wl[row * 72 + ks * 32 + g * 8];
      }
      #pragma unroll
      for (int n = 0; n < 4; ++n) {
        int row = n * 16 + lr;
        bf[n] = *(const s16x8*)&Xl[row * 72 + ks * 32 + g * 8];
      }
      #pragma unroll
      for (int m = 0; m < 4; ++m)
        #pragma unroll
        for (int n = 0; n < 4; ++n)
          acc[m][n] = __builtin_amdgcn_mfma_f32_16x16x32_bf16(af[m], bf[n], acc[m][n], 0, 0, 0);
    }
  }
  __syncthreads();
  #pragma unroll
  for (int m = 0; m < 4; ++m) {
    int ob = wid * 64 + m * 16 + g * 4;
    float4 b4 = *(const float4*)&bias[ob];
    float bb[4] = {b4.x, b4.y, b4.z, b4.w};
    #pragma unroll
    for (int n = 0; n < 4; ++n)
      #pragma unroll
      for (int r = 0; r < 4; ++r) {
        float y = acc[m][n][r] + bb[r];
        acc[m][n][r] = (ACT == 0) ? gelu_f(y) : sigmoid_f(y);
      }
  }
  #pragma unroll
  for (int ho = 0; ho < 2; ++ho) {
    __syncthreads();
    if ((wid >> 1) == ho) {
      #pragma unroll
      for (int m = 0; m < 4; ++m) {
        int ol = (wid & 1) * 64 + m * 16 + g * 4;
        #pragma unroll
        for (int n = 0; n < 4; ++n) {
          int p = n * 16 + lr, q = p >> 2;
          #pragma unroll
          for (int r = 0; r < 4; ++r) {
            int orow = ol + r;
            Tt[orow * 64 + ((q ^ (orow & 15)) << 2) + (p & 3)] = acc[m][n][r];
          }
        }
      }
    }
    __syncthreads();
    #pragma unroll
    for (int it = 0; it < 8; ++it) {
      int slot = it * 256 + t;
      int ol = slot >> 4, q = slot & 15;
      float4 v4 = *(const float4*)&Tt[ol * 64 + ((q ^ (ol & 15)) << 2)];
      u16x4 pk = {f2b(v4.x), f2b(v4.y), f2b(v4.z), f2b(v4.w)};
      int o = ho * 128 + ol;
      *(u16x4*)(out_cp + ((size_t)s * 256 + o) * HW + p0 + q * 4) = pk;
    }
  }
}

// ---------------- c-major MFMA GEMM (R9 staging), small gate GEMMs ---------
template<int ACT, int NBA, int PTA, int PTV>
__global__ __launch_bounds__(256) void mfma_pw_cm(
    const u16* __restrict__ Xa, const u16* __restrict__ Wa,
    const float* __restrict__ ba, u16* __restrict__ outa_cp,
    const u16* __restrict__ Xv, const u16* __restrict__ Wv,
    const float* __restrict__ bv, u16* __restrict__ outv_cp)
{
  __shared__ __align__(16) char smem[256 * 72 * 2 + 64 * 68 * 2];
  u16* Wl = (u16*)smem;
  u16* Xl = (u16*)smem + 256 * 72;
  float* Tt = (float*)smem;
  const int t = threadIdx.x;
  const int lane = t & 63, wid = t >> 6;
  const int g = lane >> 4, lr = lane & 15;
  int bid = blockIdx.x;
  const u16 *X, *W; const float* bias; u16* out_cp; int HW, px, s;
  if (bid < NBA) {
    X = Xa; W = Wa; bias = ba; out_cp = outa_cp;
    HW = PTA * 64; px = bid % PTA; s = bid / PTA;
  } else {
    bid -= NBA;
    X = Xv; W = Wv; bias = bv; out_cp = outv_cp;
    HW = PTV * 64; px = bid % PTV; s = bid / PTV;
  }
  const int p0 = px * 64;
  const u16* Xs = X + (size_t)s * 256 * HW + p0;
  const int cg = t >> 4, pg = t & 15;
  f32x4 acc[4][4] = {};
  u16x8 stw[8];
  u16x4 stc[4];
  #pragma unroll
  for (int it = 0; it < 8; ++it) {
    int slot = it * 256 + t, row = slot >> 3, ch = slot & 7;
    stw[it] = *(const u16x8*)(W + row * 256 + ch * 8);
  }
  #pragma unroll
  for (int cc = 0; cc < 4; ++cc)
    stc[cc] = *(const u16x4*)(Xs + (size_t)(cg * 4 + cc) * HW + pg * 4);
  for (int kt = 0; kt < 4; ++kt) {
    __syncthreads();
    #pragma unroll
    for (int it = 0; it < 8; ++it) {
      int slot = it * 256 + t, row = slot >> 3, ch = slot & 7;
      *(u16x8*)&Wl[row * 72 + ch * 8] = stw[it];
    }
    #pragma unroll
    for (int pp = 0; pp < 4; ++pp) {
      u16x4 vv = {stc[0][pp], stc[1][pp], stc[2][pp], stc[3][pp]};
      *(u16x4*)&Xl[(pg * 4 + pp) * 68 + cg * 4] = vv;
    }
    __syncthreads();
    if (kt < 3) {
      const int k1 = (kt + 1) * 64;
      #pragma unroll
      for (int it = 0; it < 8; ++it) {
        int slot = it * 256 + t, row = slot >> 3, ch = slot & 7;
        stw[it] = *(const u16x8*)(W + row * 256 + k1 + ch * 8);
      }
      #pragma unroll
      for (int cc = 0; cc < 4; ++cc)
        stc[cc] = *(const u16x4*)(Xs + (size_t)(k1 + cg * 4 + cc) * HW + pg * 4);
    }
    #pragma unroll
    for (int ks = 0; ks < 2; ++ks) {
      s16x8 af[4], bf[4];
      #pragma unroll
      for (int m = 0; m < 4; ++m) {
        int row = wid * 64 + m * 16 + lr;
        af[m] = *(const s16x8*)&Wl[row * 72 + ks * 32 + g * 8];
      }
      #pragma unroll
      for (int n = 0; n < 4; ++n) {
        int row = n * 16 + lr;
        bf[n] = *(const s16x8*)&Xl[row * 68 + ks * 32 + g * 8];
      }
      #pragma unroll
      for (int m = 0; m < 4; ++m)
        #pragma unroll
        for (int n = 0; n < 4; ++n)
          acc[m][n] = __builtin_amdgcn_mfma_f32_16x16x32_bf16(af[m], bf[n], acc[m][n], 0, 0, 0);
    }
  }
  __syncthreads();
  #pragma unroll
  for (int m = 0; m < 4; ++m) {
    int ob = wid * 64 + m * 16 + g * 4;
    float4 b4 = *(const float4*)&bias[ob];
    float bb[4] = {b4.x, b4.y, b4.z, b4.w};
    #pragma unroll
    for (int n = 0; n < 4; ++n)
      #pragma unroll
      for (int r = 0; r < 4; ++r) {
        float y = acc[m][n][r] + bb[r];
        acc[m][n][r] = (ACT == 0) ? gelu_f(y) : sigmoid_f(y);
      }
  }
  #pragma unroll
  for (int ho = 0; ho < 2; ++ho) {
    __syncthreads();
    if ((wid >> 1) == ho) {
      #pragma unroll
      for (int m = 0; m < 4; ++m) {
        int ol = (wid & 1) * 64 + m * 16 + g * 4;
        #pragma unroll
        for (int n = 0; n < 4; ++n) {
          int p = n * 16 + lr, q = p >> 2;
          #pragma unroll
          for (int r = 0; r < 4; ++r) {
            int orow = ol + r;
            Tt[orow * 64 + ((q ^ (orow & 15)) << 2) + (p & 3)] = acc[m][n][r];
          }
        }
      }
    }
    __syncthreads();
    #pragma unroll
    for (int it = 0; it < 8; ++it) {
      int slot = it * 256 + t;
      int ol = slot >> 4, q = slot & 15;
      float4 v4 = *(const float4*)&Tt[ol * 64 + ((q ^ (ol & 15)) << 2)];
      u16x4 pk = {f2b(v4.x), f2b(v4.y), f2b(v4.z), f2b(v4.w)};
      int o = ho * 128 + ol;
      *(u16x4*)(out_cp + ((size_t)s * 256 + o) * HW + p0 + q * 4) = pk;
    }
  }
}

// -------- merged T-mean pool + bilinear, CP in / CP out --------------------
__global__ __launch_bounds__(256) void pool_bilin_cp(
    const u16* __restrict__ vf_cp, u16* __restrict__ vfa_cp,
    const u16* __restrict__ af_cp, u16* __restrict__ afv_cp)
{
  const int t = threadIdx.x;
  int bid = blockIdx.x;
  if (bid < 1024) {
    int b = bid >> 8, c = bid & 255;
    u16* dst = vfa_cp + ((size_t)(b * 256 + c) << 10);
    #pragma unroll
    for (int k = 0; k < 4; ++k) {
      int idx = t + k * 256;
      int oh = idx >> 5, ow = idx & 31;
      int sh = (oh * VH_) >> 5, eh = ((oh + 1) * VH_ + 31) >> 5;
      int sw = (ow * VW_) >> 5, ew = ((ow + 1) * VW_ + 31) >> 5;
      float acc = 0.f;
      for (int tt = 0; tt < T_; ++tt) {
        const u16* base = vf_cp + ((size_t)((b * T_ + tt) * 256 + c)) * VHW;
        for (int ih = sh; ih < eh; ++ih)
          for (int iw = sw; iw < ew; ++iw)
            acc += b2f(base[ih * VW_ + iw]);
      }
      dst[idx] = f2b(acc / (float)(T_ * (eh - sh) * (ew - sw)));
    }
  } else {
    bid -= 1024;
    int b = bid >> 8, c = bid & 255;
    const u16* base = af_cp + ((size_t)(b * 256 + c) << 10);
    u16* dst = afv_cp + (size_t)(b * 256 + c) * VHW;
    const float sc = (float)AH_ / (float)VH_;
    for (int k = 0; k < 13; ++k) {
      int idx = t + k * 256;
      if (idx < VHW) {
        int oh = idx / VW_, ow = idx - oh * VW_;
        float srh = fminf(fmaxf((oh + 0.5f) * sc - 0.5f, 0.f), (float)(AH_ - 1));
        float srw = fminf(fmaxf((ow + 0.5f) * sc - 0.5f, 0.f), (float)(AW_ - 1));
        int h0 = (int)srh, w0 = (int)srw;
        int h1 = min(h0 + 1, AH_ - 1), w1 = min(w0 + 1, AW_ - 1);
        float fh = srh - (float)h0, fw = srw - (float)w0;
        float v00 = b2f(base[h0 * AW_ + w0]), v01 = b2f(base[h0 * AW_ + w1]);
        float v10 = b2f(base[h1 * AW_ + w0]), v11 = b2f(base[h1 * AW_ + w1]);
        float top = v00 + (v01 - v00) * fw;
        float bot = v10 + (v11 - v10) * fw;
        dst[idx] = f2b(top + (bot - top) * fh);
      }
    }
  }
}

// -------- merged residual gates: a (blocks 0..511) + v ---------------------
__global__ __launch_bounds__(256) void final_av(
    const float* __restrict__ a, const u16* __restrict__ afcp,
    const u16* __restrict__ gacp, const float* __restrict__ sa,
    const float* __restrict__ v, const u16* __restrict__ vfcp,
    const u16* __restrict__ gvcp, const float* __restrict__ sv,
    float* __restrict__ out)
{
  int bid = blockIdx.x;
  if (bid < 512) {
    size_t i = ((size_t)bid * 256 + threadIdx.x) * 8;
    float s = sa[0];
    float4 a0 = *(const float4*)(a + i), a1 = *(const float4*)(a + i + 4);
    u16x8 f = *(const u16x8*)(afcp + i);
    u16x8 gg = *(const u16x8*)(gacp + i);
    float4 o0 = {a0.x + s * b2f(f[0]) * b2f(gg[0]), a0.y + s * b2f(f[1]) * b2f(gg[1]),
                 a0.z + s * b2f(f[2]) * b2f(gg[2]), a0.w + s * b2f(f[3]) * b2f(gg[3])};
    float4 o1 = {a1.x + s * b2f(f[4]) * b2f(gg[4]), a1.y + s * b2f(f[5]) * b2f(gg[5]),
                 a1.z + s * b2f(f[6]) * b2f(gg[6]), a1.w + s * b2f(f[7]) * b2f(gg[7])};
    *(float4*)(out + i) = o0;
    *(float4*)(out + i + 4) = o1;
  } else {
    size_t i = ((size_t)(bid - 512) * 256 + threadIdx.x) * 8;
    const size_t PER = (size_t)C_ * VHW;
    int bt = (int)(i / PER);
    size_t rem = i - (size_t)bt * PER;
    const u16* gp = gvcp + (size_t)(bt >> 2) * PER + rem;
    float s = sv[0];
    float4 v0 = *(const float4*)(v + i), v1 = *(const float4*)(v + i + 4);
    u16x8 f = *(const u16x8*)(vfcp + i);
    u16x8 gg = *(const u16x8*)gp;
    float4 o0 = {v0.x + s * b2f(f[0]) * b2f(gg[0]), v0.y + s * b2f(f[1]) * b2f(gg[1]),
                 v0.z + s * b2f(f[2]) * b2f(gg[2]), v0.w + s * b2f(f[3]) * b2f(gg[3])};
    float4 o1 = {v1.x + s * b2f(f[4]) * b2f(gg[4]), v1.y + s * b2f(f[5]) * b2f(gg[5]),
                 v1.z + s * b2f(f[6]) * b2f(gg[6]), v1.w + s * b2f(f[7]) * b2f(gg[7])};
    float* ov = out + NA_;
    *(float4*)(ov + i) = o0;
    *(float4*)(ov + i + 4) = o1;
  }
}

// ---------------------------------------------------------------------------
extern "C" void kernel_launch(void* const* d_in, const int* in_sizes, int n_in,
                              void* d_out, int out_size, void* d_ws, size_t ws_size,
                              hipStream_t stream)
{
  const float* a        = (const float*)d_in[0];
  const float* v        = (const float*)d_in[1];
  const float* a_gn_w   = (const float*)d_in[2];
  const float* a_gn_b   = (const float*)d_in[3];
  const float* a_dw7    = (const float*)d_in[4];
  const float* a_dw3    = (const float*)d_in[5];
  const float* a_pw_w   = (const float*)d_in[6];
  const float* a_pw_b   = (const float*)d_in[7];
  const float* v_gn_w   = (const float*)d_in[8];
  const float* v_gn_b   = (const float*)d_in[9];
  const float* v_dw7    = (const float*)d_in[10];
  const float* v_dw3    = (const float*)d_in[11];
  const float* v_pw_w   = (const float*)d_in[12];
  const float* v_pw_b   = (const float*)d_in[13];
  const float* gate_a_w = (const float*)d_in[14];
  const float* gate_a_b = (const float*)d_in[15];
  const float* gate_v_w = (const float*)d_in[16];
  const float* gate_v_b = (const float*)d_in[17];
  const float* scale_a  = (const float*)d_in[18];
  const float* scale_v  = (const float*)d_in[19];
  float* out = (float*)d_out;
  char* wsb = (char*)d_ws;

  const size_t SZ_V  = (size_t)NV_ * 2;     // 25.7 MB
  const size_t SZ_AV = (size_t)NAV_ * 2;    //  6.4 MB
  const size_t SZ_A  = (size_t)NA_ * 2;     //  2.1 MB
  // region 0: dwv_b (dead after transpose) -> afv + gatev_cp aliases
  u16* dwv_b    = (u16*)(wsb + 0);
  u16* afv      = (u16*)(wsb + 0);                     // bilinear out (CP)
  u16* gatev_cp = (u16*)(wsb + SZ_AV);
  u16* dwvT     = (u16*)(wsb + SZ_V);                  // dead after GELU GEMM
  u16* vfeat_cp = (u16*)(wsb + 2 * SZ_V);
  u16* dwa_b    = (u16*)(wsb + 3 * SZ_V);
  u16* dwaT     = (u16*)(wsb + 3 * SZ_V + SZ_A);
  u16* afeat_cp = (u16*)(wsb + 3 * SZ_V + 2 * SZ_A);
  u16* vfa      = (u16*)(wsb + 3 * SZ_V + 3 * SZ_A);   // pool out (CP)
  u16* gatea_cp = (u16*)(wsb + 3 * SZ_V + 4 * SZ_A);
  u16* w_bf     = (u16*)(wsb + 3 * SZ_V + 5 * SZ_A);   // 4 * 65536 bf16
  float* pf     = (float*)(wsb + 3 * SZ_V + 5 * SZ_A + 4 * 65536 * 2);
  float* part   = pf;                                  // 5120
  float* stats  = pf + 5120;                           // 40
  u16* wA = w_bf, *wV = w_bf + 65536, *wGA = w_bf + 131072, *wGV = w_bf + 196608;

  // 1. weights -> bf16
  cvt_bf16_4<<<128, 256, 0, stream>>>(a_pw_w, v_pw_w, gate_a_w, gate_v_w, w_bf);

  // 2. GroupNorm stats
  gn_reduce1m<<<dim3(128, 20), 256, 0, stream>>>(a, v, part);
  gn_reduce2m<<<20, 128, 0, stream>>>(part, stats);

  // 3. merged GN + dwconv -> [c][p] bf16 (a: 1024, v: 4096 blocks)
  gn_dwconv_all<<<5120, 256, 0, stream>>>(a, v, stats,
      a_gn_w, a_gn_b, a_dw7, a_dw3, v_gn_w, v_gn_b, v_dw7, v_dw3, dwa_b, dwv_b);

  // 4. merged transpose to [p][c] (a: 256 blocks, v: 3136 blocks)
  transpose_all<<<3392, 256, 0, stream>>>(dwa_b, dwaT, dwv_b, dwvT);

  // 5. merged pwconv + GELU, p-major in, CP-only out (a: 64, v: 784 blocks)
  mfma_pw_pm<0, 64, 16, 49><<<848, 256, 0, stream>>>(
      dwaT, wA, a_pw_b, afeat_cp,
      dwvT, wV, v_pw_b, vfeat_cp);

  // 6. merged pool (1024) + bilinear (1024), CP in/out
  pool_bilin_cp<<<2048, 256, 0, stream>>>(vfeat_cp, vfa, afeat_cp, afv);

  // 7. merged gate GEMMs, c-major in (a: 64 + v: 196 blocks), CP out
  mfma_pw_cm<1, 64, 16, 49><<<260, 256, 0, stream>>>(
      vfa, wGA, gate_a_b, gatea_cp,
      afv, wGV, gate_v_b, gatev_cp);

  // 8. merged residual gates (a: 512, v: 6272)
  final_av<<<6784, 256, 0, stream>>>(a, afeat_cp, gatea_cp, scale_a,
                                     v, vfeat_cp, gatev_cp, scale_v, out);
}

// Round 12
// 143.445 us; speedup vs baseline: 1.1134x; 1.0943x over previous
//
#include <hip/hip_runtime.h>
#include <math.h>

#define C_   256
#define B_   4
#define T_   4
#define AH_  32
#define AW_  32
#define VH_  56
#define VW_  56
#define AHW  (AH_*AW_)          // 1024
#define VHW  (VH_*VW_)          // 3136
#define NA_  (B_*C_*AHW)        // 1,048,576
#define NV_  (B_*T_*C_*VHW)     // 12,845,056
#define NAV_ (B_*C_*VHW)        // 3,211,264

typedef unsigned short u16;
typedef short s16x8 __attribute__((ext_vector_type(8)));
typedef unsigned short u16x8 __attribute__((ext_vector_type(8)));
typedef unsigned short u16x4 __attribute__((ext_vector_type(4)));
typedef float f32x4 __attribute__((ext_vector_type(4)));

__device__ __forceinline__ u16 f2b(float f) {            // fp32 -> bf16 RNE
  unsigned u = __float_as_uint(f);
  u += 0x7FFFu + ((u >> 16) & 1u);
  return (u16)(u >> 16);
}
__device__ __forceinline__ float b2f(u16 h) {
  return __uint_as_float((unsigned)h << 16);
}
// tanh-form GELU: |err| vs exact ~3e-4
__device__ __forceinline__ float gelu_f(float x) {
  float x2 = x * x;
  float e = __expf(x * (-1.5957691216f - 0.0713548162f * x2));
  return x * __builtin_amdgcn_rcpf(1.f + e);
}
__device__ __forceinline__ float sigmoid_f(float x) {
  return __builtin_amdgcn_rcpf(1.f + __expf(-x));
}

// ------- GroupNorm stats (blocks 0..2559) + weight cvt (blocks 2560+) ------
__global__ __launch_bounds__(256) void gn_reduce1m_cvt(
    const float* __restrict__ a, const float* __restrict__ v,
    float* __restrict__ part,
    const float* __restrict__ s0, const float* __restrict__ s1,
    const float* __restrict__ s2, const float* __restrict__ s3,
    u16* __restrict__ wdst)
{
  int bid = blockIdx.x;
  if (bid < 2560) {
    int samp = bid >> 7, chunk = bid & 127;
    const float* x; int per;
    if (samp < 4) { x = a + (size_t)samp * (C_ * AHW); per = (C_ * AHW / 4) / 128; }
    else          { x = v + (size_t)(samp - 4) * (C_ * VHW); per = (C_ * VHW / 4) / 128; }
    const float4* xb = (const float4*)x + (size_t)chunk * per;
    float s = 0.f, s2 = 0.f;
    for (int i = threadIdx.x; i < per; i += 256) {
      float4 q = xb[i];
      s  += q.x + q.y + q.z + q.w;
      s2 += q.x*q.x + q.y*q.y + q.z*q.z + q.w*q.w;
    }
    __shared__ float sh1[256], sh2[256];
    sh1[threadIdx.x] = s; sh2[threadIdx.x] = s2;
    __syncthreads();
    for (int st = 128; st > 0; st >>= 1) {
      if (threadIdx.x < st) {
        sh1[threadIdx.x] += sh1[threadIdx.x + st];
        sh2[threadIdx.x] += sh2[threadIdx.x + st];
      }
      __syncthreads();
    }
    if (threadIdx.x == 0) {
      part[(samp * 128 + chunk) * 2 + 0] = sh1[0];
      part[(samp * 128 + chunk) * 2 + 1] = sh2[0];
    }
  } else {
    bid -= 2560;
    int g = bid >> 5;
    const float* src = (g == 0) ? s0 : (g == 1) ? s1 : (g == 2) ? s2 : s3;
    size_t i = ((size_t)(bid & 31) * 256 + threadIdx.x) * 8;
    float4 v0 = *(const float4*)(src + i);
    float4 v1 = *(const float4*)(src + i + 4);
    u16x8 o = {f2b(v0.x), f2b(v0.y), f2b(v0.z), f2b(v0.w),
               f2b(v1.x), f2b(v1.y), f2b(v1.z), f2b(v1.w)};
    *(u16x8*)(wdst + (size_t)g * 65536 + i) = o;
  }
}

__global__ __launch_bounds__(128) void gn_reduce2m(
    const float* __restrict__ part, float* __restrict__ stats)
{
  int samp = blockIdx.x;
  int t = threadIdx.x;
  __shared__ float sh1[128], sh2[128];
  sh1[t] = part[(samp * 128 + t) * 2 + 0];
  sh2[t] = part[(samp * 128 + t) * 2 + 1];
  __syncthreads();
  for (int st = 64; st > 0; st >>= 1) {
    if (t < st) { sh1[t] += sh1[t + st]; sh2[t] += sh2[t + st]; }
    __syncthreads();
  }
  if (t == 0) {
    float invN = (samp < 4) ? 1.f / (float)(C_ * AHW) : 1.f / (float)(C_ * VHW);
    float mu  = sh1[0] * invN;
    float var = sh2[0] * invN - mu * mu;
    stats[samp * 2 + 0] = mu;
    stats[samp * 2 + 1] = rsqrtf(var + 1e-5f);
  }
}

// ---------------- merged GN+dwconv: a-path (blocks 0..1023) + v-path -------
__global__ __launch_bounds__(256) void gn_dwconv_all(
    const float* __restrict__ xa, const float* __restrict__ xv,
    const float* __restrict__ stats,
    const float* __restrict__ a_gn_w, const float* __restrict__ a_gn_b,
    const float* __restrict__ a_dw7, const float* __restrict__ a_dw3,
    const float* __restrict__ v_gn_w, const float* __restrict__ v_gn_b,
    const float* __restrict__ v_dw7, const float* __restrict__ v_dw3,
    u16* __restrict__ outa, u16* __restrict__ outv)
{
  __shared__ float tile[62 * 64];
  __shared__ float comb[49];
  const int t = threadIdx.x;
  if (blockIdx.x < 1024) {
    constexpr int TH = 38, TW = 38, TWP = 44;
    const int nc = blockIdx.x;
    const int n = nc >> 8, c = nc & 255;
    const float mu = stats[2 * n], rstd = stats[2 * n + 1];
    const float gsc = a_gn_w[c] * rstd;
    const float gsh = a_gn_b[c] - mu * gsc;
    if (t < 49) comb[t] = a_dw7[c * 49 + t];
    __syncthreads();
    if (t < 9) comb[(t / 3) * 21 + (t % 3) * 3] += a_dw3[c * 9 + t];
    const float* xc = xa + (size_t)nc * AHW;
    for (int idx = t; idx < TH * TW; idx += 256) {
      int th = idx / TW, tw = idx - th * TW;
      int h = th - 3, w = tw - 3;
      float val = 0.f;
      if (h >= 0 && h < 32 && w >= 0 && w < 32) val = xc[h * 32 + w] * gsc + gsh;
      tile[th * TWP + tw] = val;
    }
    __syncthreads();
    if (t < 128) {
      const int rg = t >> 3, cq = t & 7;
      const int r0 = rg * 2, w0 = cq * 4;
      float acc[2][4];
      #pragma unroll
      for (int r = 0; r < 2; ++r)
        #pragma unroll
        for (int j = 0; j < 4; ++j) acc[r][j] = 0.f;
      #pragma unroll
      for (int i = 0; i < 8; ++i) {
        const float* row = &tile[(r0 + i) * TWP + w0];
        float4 ra = *(const float4*)(row);
        float4 rb = *(const float4*)(row + 4);
        float2 rc = *(const float2*)(row + 8);
        float rr[10] = {ra.x, ra.y, ra.z, ra.w, rb.x, rb.y, rb.z, rb.w, rc.x, rc.y};
        #pragma unroll
        for (int ky = 0; ky < 7; ++ky) {
          int orow = i - ky;
          if (orow >= 0 && orow < 2) {
            #pragma unroll
            for (int kx = 0; kx < 7; ++kx) {
              float wg = comb[ky * 7 + kx];
              #pragma unroll
              for (int j = 0; j < 4; ++j)
                acc[orow][j] = fmaf(rr[kx + j], wg, acc[orow][j]);
            }
          }
        }
      }
      u16* oc = outa + (size_t)nc * AHW;
      #pragma unroll
      for (int r = 0; r < 2; ++r) {
        u16x4 res = {f2b(acc[r][0]), f2b(acc[r][1]), f2b(acc[r][2]), f2b(acc[r][3])};
        *(u16x4*)&oc[(r0 + r) * 32 + w0] = res;
      }
    }
  } else {
    const int nc = blockIdx.x - 1024;
    const int n = nc >> 8, c = nc & 255;
    const float mu = stats[8 + 2 * n], rstd = stats[8 + 2 * n + 1];
    const float gsc = v_gn_w[c] * rstd;
    const float gsh = v_gn_b[c] - mu * gsc;
    if (t < 49) comb[t] = v_dw7[c * 49 + t];
    __syncthreads();
    if (t < 9) comb[(t / 3) * 21 + (t % 3) * 3] += v_dw3[c * 9 + t];
    const float* xc = xv + (size_t)nc * VHW;
    if (t < 208) {   // zero pads
      int row, q;
      if (t < 96) { int ri = t >> 4; row = (ri < 3) ? ri : ri + 56; q = t & 15; }
      else        { int r = t - 96; row = 3 + (r >> 1); q = (r & 1) ? 15 : 0; }
      int qz = q ^ (row & 7);
      f32x4 z = {0.f, 0.f, 0.f, 0.f};
      *(f32x4*)&tile[row * 64 + qz * 4] = z;
    }
    #pragma unroll
    for (int it = 0; it < 4; ++it) {
      int idx = t + it * 256;
      if (idx < 784) {
        int row = idx / 14, q = idx - row * 14;
        float4 v = *(const float4*)(xc + row * VW_ + q * 4);
        int trow = row + 3;
        int tq = (q + 1) ^ (trow & 7);
        f32x4 sv = {v.x * gsc + gsh, v.y * gsc + gsh,
                    v.z * gsc + gsh, v.w * gsc + gsh};
        *(f32x4*)&tile[trow * 64 + tq * 4] = sv;
      }
    }
    __syncthreads();
    if (t < 196) {
      const int rg = t / 14, cq = t - rg * 14;
      const int r0 = rg * 4;
      float acc[4][4];
      #pragma unroll
      for (int r = 0; r < 4; ++r)
        #pragma unroll
        for (int j = 0; j < 4; ++j) acc[r][j] = 0.f;
      #pragma unroll
      for (int i = 0; i < 10; ++i) {
        int trow = r0 + i;
        const float* rowb = &tile[trow * 64];
        int rz = trow & 7;
        float rr[12];
        #pragma unroll
        for (int k = 0; k < 3; ++k) {
          int qk = (cq + k) ^ rz;
          f32x4 rv = *(const f32x4*)(rowb + qk * 4);
          rr[4 * k + 0] = rv[0]; rr[4 * k + 1] = rv[1];
          rr[4 * k + 2] = rv[2]; rr[4 * k + 3] = rv[3];
        }
        #pragma unroll
        for (int ky = 0; ky < 7; ++ky) {
          int orow = i - ky;
          if (orow >= 0 && orow < 4) {
            #pragma unroll
            for (int kx = 0; kx < 7; ++kx) {
              float wg = comb[ky * 7 + kx];
              #pragma unroll
              for (int j = 0; j < 4; ++j)
                acc[orow][j] = fmaf(rr[j + kx + 1], wg, acc[orow][j]);
            }
          }
        }
      }
      u16* oc = outv + (size_t)nc * VHW;
      #pragma unroll
      for (int r = 0; r < 4; ++r) {
        u16x4 res = {f2b(acc[r][0]), f2b(acc[r][1]), f2b(acc[r][2]), f2b(acc[r][3])};
        *(u16x4*)&oc[(r0 + r) * VW_ + cq * 4] = res;
      }
    }
  }
}

// -------- merged bf16 transpose [S][256][HW] -> [S][HW][256], a+v ----------
__global__ __launch_bounds__(256) void transpose_all(
    const u16* __restrict__ ina, u16* __restrict__ outa,
    const u16* __restrict__ inv, u16* __restrict__ outv)
{
  __shared__ u16 tile[64 * 68];
  const int t = threadIdx.x;
  int bid = blockIdx.x;
  const u16* in; u16* outp; int HW, PT;
  if (bid < 256) { in = ina; outp = outa; HW = AHW; PT = 16; }
  else           { bid -= 256; in = inv; outp = outv; HW = VHW; PT = 49; }
  int px = bid % PT; int rem = bid / PT;
  int cy = rem & 3, s = rem >> 2;
  const int p0 = px * 64, c0 = cy * 64;
  const u16* src = in + ((size_t)s * 256 + c0) * HW + p0;
  #pragma unroll
  for (int it = 0; it < 2; ++it) {
    int slot = it * 256 + t;
    int cr = slot >> 3, ch = slot & 7;
    u16x8 v = *(const u16x8*)(src + (size_t)cr * HW + ch * 8);
    u16x4 lo = {v[0], v[1], v[2], v[3]}, hi = {v[4], v[5], v[6], v[7]};
    *(u16x4*)&tile[cr * 68 + ch * 8] = lo;
    *(u16x4*)&tile[cr * 68 + ch * 8 + 4] = hi;
  }
  __syncthreads();
  int pr = t >> 2, ch = t & 3;
  u16* dst = outp + ((size_t)s * HW + p0 + pr) * 256 + c0;
  #pragma unroll
  for (int jj = 0; jj < 2; ++jj) {
    int cb = ch * 8 + jj * 32;
    u16x8 o;
    #pragma unroll
    for (int j = 0; j < 8; ++j) o[j] = tile[(cb + j) * 68 + pr];
    *(u16x8*)(dst + cb) = o;
  }
}

// ---------------- merged pointwise MFMA GEMM (a+v halves), dual output -----
template<int ACT, int WPC, int WCP, int NBA, int PTA, int PTV>
__global__ __launch_bounds__(256) void mfma_pw2(
    const u16* __restrict__ Xa, const u16* __restrict__ Wa,
    const float* __restrict__ ba, u16* __restrict__ outa_pc, u16* __restrict__ outa_cp,
    const u16* __restrict__ Xv, const u16* __restrict__ Wv,
    const float* __restrict__ bv, u16* __restrict__ outv_pc, u16* __restrict__ outv_cp)
{
  __shared__ __align__(16) char smem[(256 * 72 + 64 * 72) * 2];   // 45 KiB
  u16* Wl = (u16*)smem;
  u16* Xl = (u16*)smem + 256 * 72;
  float* Tt = (float*)smem;
  u16*  Pc = (u16*)smem;
  const int t = threadIdx.x;
  const int lane = t & 63, wid = t >> 6;
  const int g = lane >> 4, lr = lane & 15;
  int bid = blockIdx.x;
  const u16 *X, *W; const float* bias; u16 *out_pc, *out_cp; int HW, px, s;
  if (bid < NBA) {
    X = Xa; W = Wa; bias = ba; out_pc = outa_pc; out_cp = outa_cp;
    HW = PTA * 64; px = bid % PTA; s = bid / PTA;
  } else {
    bid -= NBA;
    X = Xv; W = Wv; bias = bv; out_pc = outv_pc; out_cp = outv_cp;
    HW = PTV * 64; px = bid % PTV; s = bid / PTV;
  }
  const int p0 = px * 64;
  const u16* Xs = X + ((size_t)s * HW + p0) * 256;
  f32x4 acc[4][4] = {};
  u16x8 stw[8], stx[2];
  #pragma unroll
  for (int it = 0; it < 8; ++it) {
    int slot = it * 256 + t, row = slot >> 3, ch = slot & 7;
    stw[it] = *(const u16x8*)(W + row * 256 + ch * 8);
  }
  #pragma unroll
  for (int it = 0; it < 2; ++it) {
    int slot = it * 256 + t, row = slot >> 3, ch = slot & 7;
    stx[it] = *(const u16x8*)(Xs + (size_t)row * 256 + ch * 8);
  }
  for (int kt = 0; kt < 4; ++kt) {
    __syncthreads();
    #pragma unroll
    for (int it = 0; it < 8; ++it) {
      int slot = it * 256 + t, row = slot >> 3, ch = slot & 7;
      *(u16x8*)&Wl[row * 72 + ch * 8] = stw[it];
    }
    #pragma unroll
    for (int it = 0; it < 2; ++it) {
      int slot = it * 256 + t, row = slot >> 3, ch = slot & 7;
      *(u16x8*)&Xl[row * 72 + ch * 8] = stx[it];
    }
    __syncthreads();
    if (kt < 3) {
      const int k1 = (kt + 1) * 64;
      #pragma unroll
      for (int it = 0; it < 8; ++it) {
        int slot = it * 256 + t, row = slot >> 3, ch = slot & 7;
        stw[it] = *(const u16x8*)(W + row * 256 + k1 + ch * 8);
      }
      #pragma unroll
      for (int it = 0; it < 2; ++it) {
        int slot = it * 256 + t, row = slot >> 3, ch = slot & 7;
        stx[it] = *(const u16x8*)(Xs + (size_t)row * 256 + k1 + ch * 8);
      }
    }
    #pragma unroll
    for (int ks = 0; ks < 2; ++ks) {
      s16x8 af[4], bf[4];
      #pragma unroll
      for (int m = 0; m < 4; ++m) {
        int row = wid * 64 + m * 16 + lr;
        af[m] = *(const s16x8*)&Wl[row * 72 + ks * 32 + g * 8];
      }
      #pragma unroll
      for (int n = 0; n < 4; ++n) {
        int row = n * 16 + lr;
        bf[n] = *(const s16x8*)&Xl[row * 72 + ks * 32 + g * 8];
      }
      #pragma unroll
      for (int m = 0; m < 4; ++m)
        #pragma unroll
        for (int n = 0; n < 4; ++n)
          acc[m][n] = __builtin_amdgcn_mfma_f32_16x16x32_bf16(af[m], bf[n], acc[m][n], 0, 0, 0);
    }
  }
  __syncthreads();
  #pragma unroll
  for (int m = 0; m < 4; ++m) {
    int ob = wid * 64 + m * 16 + g * 4;
    float4 b4 = *(const float4*)&bias[ob];
    float bb[4] = {b4.x, b4.y, b4.z, b4.w};
    #pragma unroll
    for (int n = 0; n < 4; ++n)
      #pragma unroll
      for (int r = 0; r < 4; ++r) {
        float y = acc[m][n][r] + bb[r];
        acc[m][n][r] = (ACT == 0) ? gelu_f(y) : sigmoid_f(y);
      }
  }
  if (WPC) {
    #pragma unroll
    for (int m = 0; m < 4; ++m) {
      int obase = wid * 64 + m * 16 + g * 4;
      #pragma unroll
      for (int n = 0; n < 4; ++n) {
        int p = n * 16 + lr;
        int op = obase ^ ((p & 7) << 3);
        u16x4 pk = {f2b(acc[m][n][0]), f2b(acc[m][n][1]), f2b(acc[m][n][2]), f2b(acc[m][n][3])};
        *(u16x4*)&Pc[p * 256 + op] = pk;
      }
    }
    __syncthreads();
    int pr = t >> 2;
    u16* dst = out_pc + ((size_t)s * HW + p0 + pr) * 256;
    #pragma unroll
    for (int j = 0; j < 8; ++j) {
      int o = (j * 4 + (t & 3)) * 8;
      int op = o ^ ((pr & 7) << 3);
      u16x8 vv = *(const u16x8*)&Pc[pr * 256 + op];
      *(u16x8*)(dst + o) = vv;
    }
  }
  if (WCP) {
    #pragma unroll
    for (int ho = 0; ho < 2; ++ho) {
      __syncthreads();
      if ((wid >> 1) == ho) {
        #pragma unroll
        for (int m = 0; m < 4; ++m) {
          int ol = (wid & 1) * 64 + m * 16 + g * 4;
          #pragma unroll
          for (int n = 0; n < 4; ++n) {
            int p = n * 16 + lr, q = p >> 2;
            #pragma unroll
            for (int r = 0; r < 4; ++r) {
              int orow = ol + r;
              Tt[orow * 64 + ((q ^ (orow & 15)) << 2) + (p & 3)] = acc[m][n][r];
            }
          }
        }
      }
      __syncthreads();
      #pragma unroll
      for (int it = 0; it < 8; ++it) {
        int slot = it * 256 + t;
        int ol = slot >> 4, q = slot & 15;
        float4 v4 = *(const float4*)&Tt[ol * 64 + ((q ^ (ol & 15)) << 2)];
        u16x4 pk = {f2b(v4.x), f2b(v4.y), f2b(v4.z), f2b(v4.w)};
        int o = ho * 128 + ol;
        *(u16x4*)(out_cp + ((size_t)s * 256 + o) * HW + p0 + q * 4) = pk;
      }
    }
  }
}

// -------- merged T-mean pool (blocks 0..4095) + bilinear upsample ----------
__global__ __launch_bounds__(256) void pool_bilin(
    const u16* __restrict__ vf, u16* __restrict__ vfa,
    const u16* __restrict__ af, u16* __restrict__ afv)
{
  int c = threadIdx.x;
  int pb = blockIdx.x;
  if (pb < 4096) {
    int ow = pb & 31, oh = (pb >> 5) & 31, b = pb >> 10;
    int sh = (oh * VH_) >> 5, eh = ((oh + 1) * VH_ + 31) >> 5;
    int sw = (ow * VW_) >> 5, ew = ((ow + 1) * VW_ + 31) >> 5;
    float acc = 0.f;
    for (int tt = 0; tt < T_; ++tt)
      for (int ih = sh; ih < eh; ++ih)
        for (int iw = sw; iw < ew; ++iw)
          acc += b2f(vf[((size_t)(b * T_ + tt) * VHW + ih * VW_ + iw) * 256 + c]);
    vfa[(size_t)pb * 256 + c] = f2b(acc / (float)(T_ * (eh - sh) * (ew - sw)));
  } else {
    pb -= 4096;
    int ow = pb % VW_; int tmp = pb / VW_; int oh = tmp % VH_; int b = tmp / VH_;
    const float sc = (float)AH_ / (float)VH_;
    float srh = fminf(fmaxf((oh + 0.5f) * sc - 0.5f, 0.f), (float)(AH_ - 1));
    float srw = fminf(fmaxf((ow + 0.5f) * sc - 0.5f, 0.f), (float)(AW_ - 1));
    int h0 = (int)srh, w0 = (int)srw;
    int h1 = min(h0 + 1, AH_ - 1), w1 = min(w0 + 1, AW_ - 1);
    float fh = srh - (float)h0, fw = srw - (float)w0;
    const u16* base = af + (size_t)b * AHW * 256 + c;
    float v00 = b2f(base[(h0 * AW_ + w0) * 256]), v01 = b2f(base[(h0 * AW_ + w1) * 256]);
    float v10 = b2f(base[(h1 * AW_ + w0) * 256]), v11 = b2f(base[(h1 * AW_ + w1) * 256]);
    float top = v00 + (v01 - v00) * fw;
    float bot = v10 + (v11 - v10) * fw;
    afv[(size_t)pb * 256 + c] = f2b(top + (bot - top) * fh);
  }
}

// -------- merged residual gates: a (blocks 0..511) + v ---------------------
__global__ __launch_bounds__(256) void final_av(
    const float* __restrict__ a, const u16* __restrict__ afcp,
    const u16* __restrict__ gacp, const float* __restrict__ sa,
    const float* __restrict__ v, const u16* __restrict__ vfcp,
    const u16* __restrict__ gvcp, const float* __restrict__ sv,
    float* __restrict__ out)
{
  int bid = blockIdx.x;
  if (bid < 512) {
    size_t i = ((size_t)bid * 256 + threadIdx.x) * 8;
    float s = sa[0];
    float4 a0 = *(const float4*)(a + i), a1 = *(const float4*)(a + i + 4);
    u16x8 f = *(const u16x8*)(afcp + i);
    u16x8 gg = *(const u16x8*)(gacp + i);
    float4 o0 = {a0.x + s * b2f(f[0]) * b2f(gg[0]), a0.y + s * b2f(f[1]) * b2f(gg[1]),
                 a0.z + s * b2f(f[2]) * b2f(gg[2]), a0.w + s * b2f(f[3]) * b2f(gg[3])};
    float4 o1 = {a1.x + s * b2f(f[4]) * b2f(gg[4]), a1.y + s * b2f(f[5]) * b2f(gg[5]),
                 a1.z + s * b2f(f[6]) * b2f(gg[6]), a1.w + s * b2f(f[7]) * b2f(gg[7])};
    *(float4*)(out + i) = o0;
    *(float4*)(out + i + 4) = o1;
  } else {
    size_t i = ((size_t)(bid - 512) * 256 + threadIdx.x) * 8;
    const size_t PER = (size_t)C_ * VHW;
    int bt = (int)(i / PER);
    size_t rem = i - (size_t)bt * PER;
    const u16* gp = gvcp + (size_t)(bt >> 2) * PER + rem;
    float s = sv[0];
    float4 v0 = *(const float4*)(v + i), v1 = *(const float4*)(v + i + 4);
    u16x8 f = *(const u16x8*)(vfcp + i);
    u16x8 gg = *(const u16x8*)gp;
    float4 o0 = {v0.x + s * b2f(f[0]) * b2f(gg[0]), v0.y + s * b2f(f[1]) * b2f(gg[1]),
                 v0.z + s * b2f(f[2]) * b2f(gg[2]), v0.w + s * b2f(f[3]) * b2f(gg[3])};
    float4 o1 = {v1.x + s * b2f(f[4]) * b2f(gg[4]), v1.y + s * b2f(f[5]) * b2f(gg[5]),
                 v1.z + s * b2f(f[6]) * b2f(gg[6]), v1.w + s * b2f(f[7]) * b2f(gg[7])};
    float* ov = out + NA_;
    *(float4*)(ov + i) = o0;
    *(float4*)(ov + i + 4) = o1;
  }
}

// ---------------------------------------------------------------------------
extern "C" void kernel_launch(void* const* d_in, const int* in_sizes, int n_in,
                              void* d_out, int out_size, void* d_ws, size_t ws_size,
                              hipStream_t stream)
{
  const float* a        = (const float*)d_in[0];
  const float* v        = (const float*)d_in[1];
  const float* a_gn_w   = (const float*)d_in[2];
  const float* a_gn_b   = (const float*)d_in[3];
  const float* a_dw7    = (const float*)d_in[4];
  const float* a_dw3    = (const float*)d_in[5];
  const float* a_pw_w   = (const float*)d_in[6];
  const float* a_pw_b   = (const float*)d_in[7];
  const float* v_gn_w   = (const float*)d_in[8];
  const float* v_gn_b   = (const float*)d_in[9];
  const float* v_dw7    = (const float*)d_in[10];
  const float* v_dw3    = (const float*)d_in[11];
  const float* v_pw_w   = (const float*)d_in[12];
  const float* v_pw_b   = (const float*)d_in[13];
  const float* gate_a_w = (const float*)d_in[14];
  const float* gate_a_b = (const float*)d_in[15];
  const float* gate_v_w = (const float*)d_in[16];
  const float* gate_v_b = (const float*)d_in[17];
  const float* scale_a  = (const float*)d_in[18];
  const float* scale_v  = (const float*)d_in[19];
  float* out = (float*)d_out;
  char* wsb = (char*)d_ws;

  const size_t SZ_V  = (size_t)NV_ * 2;
  const size_t SZ_AV = (size_t)NAV_ * 2;
  const size_t SZ_A  = (size_t)NA_ * 2;
  u16* dwv_b    = (u16*)(wsb + 0);                     // dead after transpose_v
  u16* vfeat_cp = (u16*)(wsb + 0);                     // alias (v-GEMM output)
  u16* dwvT     = (u16*)(wsb + SZ_V);                  // dead after v-GEMM
  u16* afv      = (u16*)(wsb + SZ_V);                  // alias (bilinear out)
  u16* gatev_cp = (u16*)(wsb + SZ_V + SZ_AV);          // alias
  u16* vfeat_pc = (u16*)(wsb + 2 * SZ_V);
  u16* dwa_b    = (u16*)(wsb + 3 * SZ_V);
  u16* dwaT     = (u16*)(wsb + 3 * SZ_V + SZ_A);
  u16* afeat_pc = (u16*)(wsb + 3 * SZ_V + 2 * SZ_A);
  u16* afeat_cp = (u16*)(wsb + 3 * SZ_V + 3 * SZ_A);
  u16* vfa      = (u16*)(wsb + 3 * SZ_V + 4 * SZ_A);
  u16* gatea_cp = (u16*)(wsb + 3 * SZ_V + 5 * SZ_A);
  u16* w_bf     = (u16*)(wsb + 3 * SZ_V + 6 * SZ_A);   // 4 * 65536 bf16
  float* pf     = (float*)(wsb + 3 * SZ_V + 6 * SZ_A + 4 * 65536 * 2);
  float* part   = pf;                                  // 5120
  float* stats  = pf + 5120;                           // 40
  u16* wA = w_bf, *wV = w_bf + 65536, *wGA = w_bf + 131072, *wGV = w_bf + 196608;

  // 1. GroupNorm stats + weight cvt (one launch: 2560 + 128 blocks)
  gn_reduce1m_cvt<<<2688, 256, 0, stream>>>(a, v, part,
      a_pw_w, v_pw_w, gate_a_w, gate_v_w, w_bf);
  gn_reduce2m<<<20, 128, 0, stream>>>(part, stats);

  // 2. merged GN + dwconv (a: 1024 blocks, v: 4096 blocks)
  gn_dwconv_all<<<5120, 256, 0, stream>>>(a, v, stats,
      a_gn_w, a_gn_b, a_dw7, a_dw3, v_gn_w, v_gn_b, v_dw7, v_dw3, dwa_b, dwv_b);

  // 3. merged transpose to [p][c] (a: 256 blocks, v: 3136 blocks)
  transpose_all<<<3392, 256, 0, stream>>>(dwa_b, dwaT, dwv_b, dwvT);

  // 4. merged pwconv + GELU, dual-layout outputs (a: 64, v: 784 blocks)
  mfma_pw2<0, 1, 1, 64, 16, 49><<<848, 256, 0, stream>>>(
      dwaT, wA, a_pw_b, afeat_pc, afeat_cp,
      dwvT, wV, v_pw_b, vfeat_pc, vfeat_cp);

  // 5. merged pool (4096) + bilinear (12544), pc layouts
  pool_bilin<<<16640, 256, 0, stream>>>(vfeat_pc, vfa, afeat_pc, afv);

  // 6. merged gate GEMMs: gate_a (64) + gate_v (196), sigmoid, CP-only
  mfma_pw2<1, 0, 1, 64, 16, 49><<<260, 256, 0, stream>>>(
      vfa, wGA, gate_a_b, nullptr, gatea_cp,
      afv, wGV, gate_v_b, nullptr, gatev_cp);

  // 7. merged residual gates (a: 512, v: 6272)
  final_av<<<6784, 256, 0, stream>>>(a, afeat_cp, gatea_cp, scale_a,
                                     v, vfeat_cp, gatev_cp, scale_v, out);
}